// Round 16
// baseline (65.519 us; speedup 1.0000x reference)
//
#include <hip/hip_runtime.h>

// ---------------------------------------------------------------------------
// Fused GAT module, fp16 MFMA (16x16x32). R16 = R15 + three latency/allocator
// squeezes (diagnosis: all pipes <35%, wave-level dependency chains + the
// (512,3)->85-VGPR allocator squeeze are the remaining cost):
//   1. launch_bounds (512,2): cap 128. At ~100 VGPR demand the HW occupancy
//      tier is 4 waves/SIMD (16 waves/CU) regardless, so the 85-cap bought
//      nothing except allocator pressure. Spill tripwire: WRITE_SIZE.
//   2. T1 XCD-aware block swizzle (2048%8==0 -> bijective simple form):
//      consecutive items share an XCD's L2.
//   3. Epilogue weight LDS reads (Wa/Wvo/bvo) hoisted above the MLP so their
//      latency hides under MFMA work.
// Carried from R15: self-encode fused into main as a third MFMA row-tile
// (weight regs reused, es g-reduced+broadcast); obs loads issued BEFORE the
// weight stage; folded epilogue via Wvo fp16 A-frags; b1 folded into W1 col
// 83; rcp divides; no softmax max-sub (|e| bounded ~7).
// Persistent variants (R9/R10/R12/R13) all spilled -> permanently abandoned.
//
// Layout facts used (HW-verified per guide):
//   A-frag: lane l holds A[row = l&15][k = slot(l>>4, i)]
//   B-frag: lane l holds B[k = slot(l>>4, i)][col = l&15]
//   D:      lane l, reg r holds D[4*(l>>4)+r][l&15]
// slot() identical for A and B, so any consistent per-(group,i) k-map works.
// ---------------------------------------------------------------------------

typedef _Float16 half8 __attribute__((ext_vector_type(8)));
typedef __fp16 fp16x2 __attribute__((ext_vector_type(2)));
typedef __fp16 fp16x8 __attribute__((ext_vector_type(8)));
typedef float f32x4 __attribute__((ext_vector_type(4)));

// packed+aligned(4) wrapper: lets the backend emit dwordx4 at 4B alignment
struct __attribute__((packed, aligned(4))) F4 { f32x4 v; };

__device__ __forceinline__ f32x4 ld4(const float* p) {
    return ((const F4*)p)->v;
}

#define MFMA16(a, b, c) __builtin_amdgcn_mfma_f32_16x16x32_f16((a), (b), (c), 0, 0, 0)

// workspace byte offsets (all 16B aligned).
// [0, 51264) is the main-kernel staged region (one linear copy):
#define WS_W1F    0       // 8*3*64*8 half  = 24576 B
#define WS_W2F    24576   // 4*4*64*8 half  = 16384 B
#define WS_WVO16  40960   // 2*64*8 half    =  2048 B  (Wv@Wo fp16 A-frags)
#define WS_WAFN   43008   // 4*64 f32x4     =  4096 B  (Wa_nbr  [om][lane][c])
#define WS_WASF   47104   // 4*64 f32x4     =  4096 B  (Wa_self [om][lane][c])
#define WS_BVO    51200   // 16 f32         =    64 B
#define WS_STAGE  51264   // staged bytes (== 3204 f32x4)

__device__ __forceinline__ half8 pack8(float a0, float a1, float a2, float a3,
                                       float a4, float a5, float a6, float a7) {
    fp16x2 p0 = __builtin_amdgcn_cvt_pkrtz(a0, a1);
    fp16x2 p1 = __builtin_amdgcn_cvt_pkrtz(a2, a3);
    fp16x2 p2 = __builtin_amdgcn_cvt_pkrtz(a4, a5);
    fp16x2 p3 = __builtin_amdgcn_cvt_pkrtz(a6, a7);
    fp16x8 h;
    h[0] = p0[0]; h[1] = p0[1]; h[2] = p1[0]; h[3] = p1[1];
    h[4] = p2[0]; h[5] = p2[1]; h[6] = p3[0]; h[7] = p3[1];
    return __builtin_bit_cast(half8, h);
}

// ---------------------------------------------------------------------------
// Prep: frag-ordered fp16 weights + folded epilogue weights.
// Threads used: 23568 (grid 93 x 256).
// ---------------------------------------------------------------------------
__global__ void prep_kernel(const float* __restrict__ W1, const float* __restrict__ b1,
                            const float* __restrict__ W2, const float* __restrict__ Wv,
                            const float* __restrict__ Wa, const float* __restrict__ Wo,
                            const float* __restrict__ bv, const float* __restrict__ bo,
                            char* __restrict__ ws) {
    int t = blockIdx.x * 256 + threadIdx.x;
    _Float16* W1f = (_Float16*)(ws + WS_W1F);
    _Float16* W2f = (_Float16*)(ws + WS_W2F);
    _Float16* Wvo16 = (_Float16*)(ws + WS_WVO16);
    float* Wafn = (float*)(ws + WS_WAFN);
    float* Wasf = (float*)(ws + WS_WASF);
    float* bvo  = (float*)(ws + WS_BVO);

    if (t < 12288) {
        // W1f[hm][kt][lane][i] = W1^T[16hm+m][32kt+8g+i]; k==83 carries b1
        int i = t & 7, lane = (t >> 3) & 63, rest = t >> 9;
        int kt = rest % 3, hm = rest / 3;
        int g = lane >> 4, m = lane & 15;
        int k = 32 * kt + 8 * g + i, h = 16 * hm + m;
        float v = (k < 83) ? W1[k * 128 + h] : (k == 83 ? b1[h] : 0.f);
        W1f[t] = (_Float16)v;
    } else if (t < 20480) {
        // W2f[om][kt][lane][i] = W2[h(kt,g,i)][16om+m], h matches acc1 layout
        int u = t - 12288;
        int i = u & 7, lane = (u >> 3) & 63, rest = u >> 9;
        int kt = rest & 3, om = rest >> 2;
        int g = lane >> 4, m = lane & 15;
        int h = 16 * (2 * kt + (i >> 2)) + 4 * g + (i & 3);
        W2f[u] = (_Float16)W2[h * 64 + 16 * om + m];
    } else if (t < 21504) {
        // Wvo16[kt][lane][i] = fp16( (Wv@Wo)[o(kt,g,i)][m] ), A-frag order
        int u = t - 20480;
        int i = u & 7, lane = (u >> 3) & 63, kt = u >> 9;
        int g = lane >> 4, m = lane & 15;
        int o = 16 * (2 * kt + (i >> 2)) + 4 * g + (i & 3);
        float acc = 0.f;
#pragma unroll 8
        for (int k = 0; k < 64; ++k) acc += Wv[o * 64 + k] * Wo[k * 16 + m];
        Wvo16[u] = (_Float16)acc;
    } else if (t < 22528) {
        // Wafn[om][lane][c] = Wa_nbr[16om + 4g + c]  (b128-per-om layout)
        int u = t - 21504;
        int c = u & 3, lane = (u >> 2) & 63, om = u >> 8;
        int g = lane >> 4;
        Wafn[u] = Wa[64 + 16 * om + 4 * g + c];
    } else if (t < 23552) {
        // Wasf[om][lane][c] = Wa_self[16om + 4g + c]
        int u = t - 22528;
        int c = u & 3, lane = (u >> 2) & 63, om = u >> 8;
        int g = lane >> 4;
        Wasf[u] = Wa[16 * om + 4 * g + c];
    } else if (t < 23568) {
        int u = t - 23552;            // bvo[j] = bv@Wo + bo
        float s = bo[u];
#pragma unroll 8
        for (int k = 0; k < 64; ++k) s += bv[k] * Wo[k * 16 + u];
        bvo[u] = s;
    }
}

// ---------------------------------------------------------------------------
// Issue the 12 obs dwordx4 loads for one item (raw registers, no processing).
// Lane (g,m): rows 16rn+m, col slice 8g. g==2 tail uses ld4(rp+79) (in-row,
// elems 79..82); g==3 loads row start (dummy, discarded).
// ---------------------------------------------------------------------------
__device__ __forceinline__ void load_raw(const float* __restrict__ src,
                                         int g, int m, f32x4 raw[2][6]) {
#pragma unroll
    for (int rn = 0; rn < 2; ++rn) {
        const float* rp = src + (16 * rn + m) * 83;
        raw[rn][0] = ld4(rp + 8 * g);
        raw[rn][1] = ld4(rp + 8 * g + 4);
        raw[rn][2] = ld4(rp + 32 + 8 * g);
        raw[rn][3] = ld4(rp + 32 + 8 * g + 4);
        const float* p2 = (g < 2) ? (rp + 64 + 8 * g) : (g == 2 ? rp + 79 : rp);
        raw[rn][4] = ld4(p2);
        raw[rn][5] = ld4((g < 2) ? p2 + 4 : p2);
    }
}

// single row (self_obs): same g-slicing, 6 loads (L1-local across m-lanes)
__device__ __forceinline__ void load_raw1(const float* __restrict__ rp,
                                          int g, f32x4 raw1[6]) {
    raw1[0] = ld4(rp + 8 * g);
    raw1[1] = ld4(rp + 8 * g + 4);
    raw1[2] = ld4(rp + 32 + 8 * g);
    raw1[3] = ld4(rp + 32 + 8 * g + 4);
    const float* p2 = (g < 2) ? (rp + 64 + 8 * g) : (g == 2 ? rp + 79 : rp);
    raw1[4] = ld4(p2);
    raw1[5] = ld4((g < 2) ? p2 + 4 : p2);
}

// ---------------------------------------------------------------------------
// Convert raw obs registers -> X^T B-frags (bias-1 at k=83, zeros beyond).
// ---------------------------------------------------------------------------
__device__ __forceinline__ void pack_row(const f32x4 r0, const f32x4 r1,
                                         const f32x4 r2, const f32x4 r3,
                                         const f32x4 r4, const f32x4 r5,
                                         int g, half8 xf[3]) {
    const half8 hz = {0, 0, 0, 0, 0, 0, 0, 0};
    xf[0] = pack8(r0[0], r0[1], r0[2], r0[3], r1[0], r1[1], r1[2], r1[3]);
    xf[1] = pack8(r2[0], r2[1], r2[2], r2[3], r3[0], r3[1], r3[2], r3[3]);
    if (g < 2) {
        xf[2] = pack8(r4[0], r4[1], r4[2], r4[3], r5[0], r5[1], r5[2], r5[3]);
    } else if (g == 2) {
        // r4 = elems 79,80,81,82 ; k=80..82 + bias-1 at k=83
        xf[2] = pack8(r4[1], r4[2], r4[3], 1.f, 0.f, 0.f, 0.f, 0.f);
    } else {
        xf[2] = hz;
    }
}

// ---------------------------------------------------------------------------
// Main kernel: 2048 blocks x 512 thr, one item per wave, XCD-swizzled ids.
// Async-split obs loads; self row as third MFMA row-tile (weight reg reuse);
// MFMA epilogue (Wvo fp16 A-frags); epilogue weights hoisted above the MLP.
// ---------------------------------------------------------------------------
__global__ void __launch_bounds__(512, 2)
main_kernel(const float* __restrict__ sobs,
            const float* __restrict__ nbr,
            const float* __restrict__ edgew,
            const float* __restrict__ b2,
            const float* __restrict__ ba,
            const char* __restrict__ ws,
            float* __restrict__ out) {
    __shared__ __align__(16) char wlds[WS_STAGE];
    int tid = threadIdx.x, w = tid >> 6, lane = tid & 63;
    // T1: XCD-aware swizzle (2048 % 8 == 0 -> bijective): consecutive swz-ids
    // stay on one XCD, so each XCD reads a contiguous nbr range via its L2.
    int bid = (int)blockIdx.x;
    int swz = (bid & 7) * 256 + (bid >> 3);
    int b = swz * 8 + w;
    int g = lane >> 4, m = lane & 15;
    const f32x4 zz = {0.f, 0.f, 0.f, 0.f};

    // ---- A: issue all per-item global loads FIRST ----
    f32x4 raw[2][6];
    load_raw(nbr + (size_t)b * 2656, g, m, raw);
    f32x4 raw1[6];
    load_raw1(sobs + (size_t)b * 83, g, raw1);
    float ew0 = edgew[b * 32 + m];
    float ew1 = edgew[b * 32 + 16 + m];
    float bav = ba[0];

    // ---- B: stage weights; barrier drains stage AND obs loads together ----
    {
        const f32x4* s4 = (const f32x4*)ws;
        f32x4* d4 = (f32x4*)wlds;
#pragma unroll
        for (int t = 0; t < 6; ++t) d4[t * 512 + tid] = s4[t * 512 + tid];
        if (tid < 132) d4[3072 + tid] = s4[3072 + tid];
        __syncthreads();
    }

    // ---- B2: hoist epilogue weight reads; latency hides under the MLP ----
    const f32x4* Wafn2 = (const f32x4*)(wlds + WS_WAFN);
    const f32x4* Wasf2 = (const f32x4*)(wlds + WS_WASF);
    const half8* Wvo16 = (const half8*)(wlds + WS_WVO16);
    const float* bvo   = (const float*)(wlds + WS_BVO);
    half8 wv0 = Wvo16[lane];
    half8 wv1 = Wvo16[64 + lane];
    f32x4 wan[4], was[4];
#pragma unroll
    for (int om = 0; om < 4; ++om) {
        wan[om] = Wafn2[om * 64 + lane];
        was[om] = Wasf2[om * 64 + lane];
    }

    // ---- C: pack frags. Self tile: row 0 = self obs (m==0 cols), else 0 ----
    half8 xf[2][3], xfs[3];
    pack_row(raw[0][0], raw[0][1], raw[0][2], raw[0][3], raw[0][4], raw[0][5], g, xf[0]);
    pack_row(raw[1][0], raw[1][1], raw[1][2], raw[1][3], raw[1][4], raw[1][5], g, xf[1]);
    {
        const half8 hz = {0, 0, 0, 0, 0, 0, 0, 0};
        half8 tmp[3];
        pack_row(raw1[0], raw1[1], raw1[2], raw1[3], raw1[4], raw1[5], g, tmp);
        bool valid = (m == 0);
#pragma unroll
        for (int kt = 0; kt < 3; ++kt) xfs[kt] = valid ? tmp[kt] : hz;
    }

    const half8* W1f = (const half8*)(wlds + WS_W1F);
    const half8* W2f = (const half8*)(wlds + WS_W2F);

    // ---- D: layer 1 (neighbors rn=0,1 + self tile share weight regs) ----
    half8 hf[4][2], hfs[4];
#pragma unroll
    for (int t = 0; t < 4; ++t) {
        int h0 = 2 * t, h1 = 2 * t + 1;
        half8 u0 = W1f[(h0 * 3 + 0) * 64 + lane];
        half8 u1 = W1f[(h0 * 3 + 1) * 64 + lane];
        half8 u2 = W1f[(h0 * 3 + 2) * 64 + lane];
        half8 v0 = W1f[(h1 * 3 + 0) * 64 + lane];
        half8 v1 = W1f[(h1 * 3 + 1) * 64 + lane];
        half8 v2 = W1f[(h1 * 3 + 2) * 64 + lane];
#pragma unroll
        for (int rn = 0; rn < 2; ++rn) {
            f32x4 a = zz, c = zz;
            a = MFMA16(u0, xf[rn][0], a);
            a = MFMA16(u1, xf[rn][1], a);
            a = MFMA16(u2, xf[rn][2], a);
            c = MFMA16(v0, xf[rn][0], c);
            c = MFMA16(v1, xf[rn][1], c);
            c = MFMA16(v2, xf[rn][2], c);
            hf[t][rn] = pack8(
                fmaxf(a[0], 0.f), fmaxf(a[1], 0.f), fmaxf(a[2], 0.f), fmaxf(a[3], 0.f),
                fmaxf(c[0], 0.f), fmaxf(c[1], 0.f), fmaxf(c[2], 0.f), fmaxf(c[3], 0.f));
        }
        {   // self tile, same weights (already in registers)
            f32x4 a = zz, c = zz;
            a = MFMA16(u0, xfs[0], a);
            a = MFMA16(u1, xfs[1], a);
            a = MFMA16(u2, xfs[2], a);
            c = MFMA16(v0, xfs[0], c);
            c = MFMA16(v1, xfs[1], c);
            c = MFMA16(v2, xfs[2], c);
            hfs[t] = pack8(
                fmaxf(a[0], 0.f), fmaxf(a[1], 0.f), fmaxf(a[2], 0.f), fmaxf(a[3], 0.f),
                fmaxf(c[0], 0.f), fmaxf(c[1], 0.f), fmaxf(c[2], 0.f), fmaxf(c[3], 0.f));
        }
    }

    // ---- E: layer 2 + tanh; self path folds straight into es ----
    float I[4][2][4];
    float es_acc = 0.f;
#pragma unroll
    for (int om = 0; om < 4; ++om) {
        half8 w0 = W2f[(om * 4 + 0) * 64 + lane];
        half8 w1 = W2f[(om * 4 + 1) * 64 + lane];
        half8 w2 = W2f[(om * 4 + 2) * 64 + lane];
        half8 w3 = W2f[(om * 4 + 3) * 64 + lane];
        float b2v[4];
#pragma unroll
        for (int r = 0; r < 4; ++r) b2v[r] = b2[16 * om + 4 * g + r];
#pragma unroll
        for (int rn = 0; rn < 2; ++rn) {
            f32x4 a = zz;
            a = MFMA16(w0, hf[0][rn], a);
            a = MFMA16(w1, hf[1][rn], a);
            a = MFMA16(w2, hf[2][rn], a);
            a = MFMA16(w3, hf[3][rn], a);
#pragma unroll
            for (int r = 0; r < 4; ++r) {
                float y = a[r] + b2v[r];
                float e = __expf(2.f * y);
                I[om][rn][r] = fmaf(-2.f, __builtin_amdgcn_rcpf(e + 1.f), 1.f);
            }
        }
        {   // self: tanh + dot with Wa_self (valid in m==0 lanes)
            f32x4 a = zz;
            a = MFMA16(w0, hfs[0], a);
            a = MFMA16(w1, hfs[1], a);
            a = MFMA16(w2, hfs[2], a);
            a = MFMA16(w3, hfs[3], a);
#pragma unroll
            for (int r = 0; r < 4; ++r) {
                float y = a[r] + b2v[r];
                float e = __expf(2.f * y);
                float iv = fmaf(-2.f, __builtin_amdgcn_rcpf(e + 1.f), 1.f);
                es_acc = fmaf(iv, was[om][r], es_acc);
            }
        }
    }
    // g-reduce then broadcast from lane 0 (g0,m0 holds the full self dot)
    es_acc += __shfl_xor(es_acc, 16);
    es_acc += __shfl_xor(es_acc, 32);
    float esb = __shfl(es_acc, 0);

    // attention logits: en[row] = dot(I[row], Wa_nbr) — weights preloaded
    float en0 = 0.f, en1 = 0.f;
#pragma unroll
    for (int om = 0; om < 4; ++om) {
#pragma unroll
        for (int r = 0; r < 4; ++r) {
            en0 = fmaf(I[om][0][r], wan[om][r], en0);
            en1 = fmaf(I[om][1][r], wan[om][r], en1);
        }
    }
    en0 += __shfl_xor(en0, 16); en0 += __shfl_xor(en0, 32);
    en1 += __shfl_xor(en1, 16); en1 += __shfl_xor(en1, 32);

    float e0 = esb + en0 + bav; e0 = (e0 > 0.f) ? e0 : 0.2f * e0; e0 *= ew0;
    float e1 = esb + en1 + bav; e1 = (e1 > 0.f) ? e1 : 0.2f * e1; e1 *= ew1;

    // softmax over 32 neighbors; |e| bounded (~7) -> fp32-safe w/o max-sub
    float p0 = __expf(e0), p1 = __expf(e1);
    float s = p0 + p1;
#pragma unroll
    for (int msk = 1; msk <= 8; msk <<= 1) s += __shfl_xor(s, msk);
    float inv = __builtin_amdgcn_rcpf(s);
    float a0 = p0 * inv, a1 = p1 * inv;

    // values: V' = Wvo^T @ I^T (4 MFMAs). B-frag straight from I registers.
    half8 vf[2][2];
#pragma unroll
    for (int kt = 0; kt < 2; ++kt)
#pragma unroll
        for (int rn = 0; rn < 2; ++rn)
            vf[kt][rn] = pack8(I[2 * kt][rn][0], I[2 * kt][rn][1],
                               I[2 * kt][rn][2], I[2 * kt][rn][3],
                               I[2 * kt + 1][rn][0], I[2 * kt + 1][rn][1],
                               I[2 * kt + 1][rn][2], I[2 * kt + 1][rn][3]);

    f32x4 acc0 = zz, acc1 = zz;
    acc0 = MFMA16(wv0, vf[0][0], acc0);
    acc0 = MFMA16(wv1, vf[1][0], acc0);
    acc1 = MFMA16(wv0, vf[0][1], acc1);
    acc1 = MFMA16(wv1, vf[1][1], acc1);
    // lane (g,m) reg r: acc0[r] = V'[j=4g+r][neighbor m], acc1: neighbor 16+m

    // alpha-weight per lane, reduce over the 16 m-lanes (4 shuffle steps)
    f32x4 v4;
#pragma unroll
    for (int r = 0; r < 4; ++r) v4[r] = a0 * acc0[r] + a1 * acc1[r];
#pragma unroll
    for (int msk = 1; msk <= 8; msk <<= 1) {
#pragma unroll
        for (int r = 0; r < 4; ++r) v4[r] += __shfl_xor(v4[r], msk);
    }

    if (m == 0) {
        f32x4 bb = *(const f32x4*)(bvo + 4 * g);
        *(f32x4*)(out + (size_t)b * 16 + 4 * g) = v4 + bb;
    }
}

// ---------------------------------------------------------------------------
extern "C" void kernel_launch(void* const* d_in, const int* in_sizes, int n_in,
                              void* d_out, int out_size, void* d_ws, size_t ws_size,
                              hipStream_t stream) {
    const float* self_obs = (const float*)d_in[0];
    const float* nbr      = (const float*)d_in[1];
    const float* ew       = (const float*)d_in[2];
    const float* W1       = (const float*)d_in[3];
    const float* b1       = (const float*)d_in[4];
    const float* W2       = (const float*)d_in[5];
    const float* b2       = (const float*)d_in[6];
    const float* Wa       = (const float*)d_in[7];
    const float* ba       = (const float*)d_in[8];
    const float* Wv       = (const float*)d_in[9];
    const float* bv       = (const float*)d_in[10];
    const float* Wo       = (const float*)d_in[11];
    const float* bo       = (const float*)d_in[12];
    char* ws = (char*)d_ws;
    float* out = (float*)d_out;

    prep_kernel<<<93, 256, 0, stream>>>(W1, b1, W2, Wv, Wa, Wo, bv, bo, ws);
    main_kernel<<<2048, 512, 0, stream>>>(self_obs, nbr, ew, b2, ba, ws, out);
}

// Round 17
// 53.827 us; speedup vs baseline: 1.2172x; 1.2172x over previous
//
#include <hip/hip_runtime.h>

// ---------------------------------------------------------------------------
// Fused GAT module, fp16 MFMA (16x16x32). R17 = EXACT REVERT TO R15 (best,
// 53.9us). R16 bundled three changes (epilogue-weight hoist, (512,2) cap
// relax, XCD swizzle) and regressed to 65.5us; the hoist's +40-VGPR live
// range across the MLP is the prime suspect. Re-establishing the known-good
// configuration with zero new variables.
// Structure: prep + single fused main (2048 blocks x 512 thr, one item/wave):
//   - self-encode fused as a third MFMA row-tile reusing in-register weights;
//     es g-reduced + broadcast in-wave (no self_kernel, no es round-trip)
//   - obs loads issued BEFORE the 51264B weight stage; barrier drains both
//   - weights block-shared in LDS; b1 folded into W1 col 83
//   - folded epilogue: out = wI @ (Wv@Wo) + (bv@Wo+bo) via fp16 Wvo A-frags
//   - rcp divides; no softmax max-sub (|e| bounded ~7, fp32-safe)
// Persistent variants (R9/R10/R12/R13) spilled -> permanently abandoned.
//
// Layout facts used (HW-verified per guide):
//   A-frag: lane l holds A[row = l&15][k = slot(l>>4, i)]
//   B-frag: lane l holds B[k = slot(l>>4, i)][col = l&15]
//   D:      lane l, reg r holds D[4*(l>>4)+r][l&15]
// slot() identical for A and B, so any consistent per-(group,i) k-map works.
// ---------------------------------------------------------------------------

typedef _Float16 half8 __attribute__((ext_vector_type(8)));
typedef __fp16 fp16x2 __attribute__((ext_vector_type(2)));
typedef __fp16 fp16x8 __attribute__((ext_vector_type(8)));
typedef float f32x4 __attribute__((ext_vector_type(4)));

// packed+aligned(4) wrapper: lets the backend emit dwordx4 at 4B alignment
struct __attribute__((packed, aligned(4))) F4 { f32x4 v; };

__device__ __forceinline__ f32x4 ld4(const float* p) {
    return ((const F4*)p)->v;
}

#define MFMA16(a, b, c) __builtin_amdgcn_mfma_f32_16x16x32_f16((a), (b), (c), 0, 0, 0)

// workspace byte offsets (all 16B aligned).
// [0, 51264) is the main-kernel staged region (one linear copy):
#define WS_W1F    0       // 8*3*64*8 half  = 24576 B
#define WS_W2F    24576   // 4*4*64*8 half  = 16384 B
#define WS_WVO16  40960   // 2*64*8 half    =  2048 B  (Wv@Wo fp16 A-frags)
#define WS_WAFN   43008   // 4*64 f32x4     =  4096 B  (Wa_nbr  [om][lane][c])
#define WS_WASF   47104   // 4*64 f32x4     =  4096 B  (Wa_self [om][lane][c])
#define WS_BVO    51200   // 16 f32         =    64 B
#define WS_STAGE  51264   // staged bytes (== 3204 f32x4)

__device__ __forceinline__ half8 pack8(float a0, float a1, float a2, float a3,
                                       float a4, float a5, float a6, float a7) {
    fp16x2 p0 = __builtin_amdgcn_cvt_pkrtz(a0, a1);
    fp16x2 p1 = __builtin_amdgcn_cvt_pkrtz(a2, a3);
    fp16x2 p2 = __builtin_amdgcn_cvt_pkrtz(a4, a5);
    fp16x2 p3 = __builtin_amdgcn_cvt_pkrtz(a6, a7);
    fp16x8 h;
    h[0] = p0[0]; h[1] = p0[1]; h[2] = p1[0]; h[3] = p1[1];
    h[4] = p2[0]; h[5] = p2[1]; h[6] = p3[0]; h[7] = p3[1];
    return __builtin_bit_cast(half8, h);
}

// ---------------------------------------------------------------------------
// Prep: frag-ordered fp16 weights + folded epilogue weights.
// Threads used: 23568 (grid 93 x 256).
// ---------------------------------------------------------------------------
__global__ void prep_kernel(const float* __restrict__ W1, const float* __restrict__ b1,
                            const float* __restrict__ W2, const float* __restrict__ Wv,
                            const float* __restrict__ Wa, const float* __restrict__ Wo,
                            const float* __restrict__ bv, const float* __restrict__ bo,
                            char* __restrict__ ws) {
    int t = blockIdx.x * 256 + threadIdx.x;
    _Float16* W1f = (_Float16*)(ws + WS_W1F);
    _Float16* W2f = (_Float16*)(ws + WS_W2F);
    _Float16* Wvo16 = (_Float16*)(ws + WS_WVO16);
    float* Wafn = (float*)(ws + WS_WAFN);
    float* Wasf = (float*)(ws + WS_WASF);
    float* bvo  = (float*)(ws + WS_BVO);

    if (t < 12288) {
        // W1f[hm][kt][lane][i] = W1^T[16hm+m][32kt+8g+i]; k==83 carries b1
        int i = t & 7, lane = (t >> 3) & 63, rest = t >> 9;
        int kt = rest % 3, hm = rest / 3;
        int g = lane >> 4, m = lane & 15;
        int k = 32 * kt + 8 * g + i, h = 16 * hm + m;
        float v = (k < 83) ? W1[k * 128 + h] : (k == 83 ? b1[h] : 0.f);
        W1f[t] = (_Float16)v;
    } else if (t < 20480) {
        // W2f[om][kt][lane][i] = W2[h(kt,g,i)][16om+m], h matches acc1 layout
        int u = t - 12288;
        int i = u & 7, lane = (u >> 3) & 63, rest = u >> 9;
        int kt = rest & 3, om = rest >> 2;
        int g = lane >> 4, m = lane & 15;
        int h = 16 * (2 * kt + (i >> 2)) + 4 * g + (i & 3);
        W2f[u] = (_Float16)W2[h * 64 + 16 * om + m];
    } else if (t < 21504) {
        // Wvo16[kt][lane][i] = fp16( (Wv@Wo)[o(kt,g,i)][m] ), A-frag order
        int u = t - 20480;
        int i = u & 7, lane = (u >> 3) & 63, kt = u >> 9;
        int g = lane >> 4, m = lane & 15;
        int o = 16 * (2 * kt + (i >> 2)) + 4 * g + (i & 3);
        float acc = 0.f;
#pragma unroll 8
        for (int k = 0; k < 64; ++k) acc += Wv[o * 64 + k] * Wo[k * 16 + m];
        Wvo16[u] = (_Float16)acc;
    } else if (t < 22528) {
        // Wafn[om][lane][c] = Wa_nbr[16om + 4g + c]  (b128-per-om layout)
        int u = t - 21504;
        int c = u & 3, lane = (u >> 2) & 63, om = u >> 8;
        int g = lane >> 4;
        Wafn[u] = Wa[64 + 16 * om + 4 * g + c];
    } else if (t < 23552) {
        // Wasf[om][lane][c] = Wa_self[16om + 4g + c]
        int u = t - 22528;
        int c = u & 3, lane = (u >> 2) & 63, om = u >> 8;
        int g = lane >> 4;
        Wasf[u] = Wa[16 * om + 4 * g + c];
    } else if (t < 23568) {
        int u = t - 23552;            // bvo[j] = bv@Wo + bo
        float s = bo[u];
#pragma unroll 8
        for (int k = 0; k < 64; ++k) s += bv[k] * Wo[k * 16 + u];
        bvo[u] = s;
    }
}

// ---------------------------------------------------------------------------
// Issue the 12 obs dwordx4 loads for one item (raw registers, no processing).
// Lane (g,m): rows 16rn+m, col slice 8g. g==2 tail uses ld4(rp+79) (in-row,
// elems 79..82); g==3 loads row start (dummy, discarded).
// ---------------------------------------------------------------------------
__device__ __forceinline__ void load_raw(const float* __restrict__ src,
                                         int g, int m, f32x4 raw[2][6]) {
#pragma unroll
    for (int rn = 0; rn < 2; ++rn) {
        const float* rp = src + (16 * rn + m) * 83;
        raw[rn][0] = ld4(rp + 8 * g);
        raw[rn][1] = ld4(rp + 8 * g + 4);
        raw[rn][2] = ld4(rp + 32 + 8 * g);
        raw[rn][3] = ld4(rp + 32 + 8 * g + 4);
        const float* p2 = (g < 2) ? (rp + 64 + 8 * g) : (g == 2 ? rp + 79 : rp);
        raw[rn][4] = ld4(p2);
        raw[rn][5] = ld4((g < 2) ? p2 + 4 : p2);
    }
}

// single row (self_obs): same g-slicing, 6 loads (L1-local across m-lanes)
__device__ __forceinline__ void load_raw1(const float* __restrict__ rp,
                                          int g, f32x4 raw1[6]) {
    raw1[0] = ld4(rp + 8 * g);
    raw1[1] = ld4(rp + 8 * g + 4);
    raw1[2] = ld4(rp + 32 + 8 * g);
    raw1[3] = ld4(rp + 32 + 8 * g + 4);
    const float* p2 = (g < 2) ? (rp + 64 + 8 * g) : (g == 2 ? rp + 79 : rp);
    raw1[4] = ld4(p2);
    raw1[5] = ld4((g < 2) ? p2 + 4 : p2);
}

// ---------------------------------------------------------------------------
// Convert raw obs registers -> X^T B-frags (bias-1 at k=83, zeros beyond).
// ---------------------------------------------------------------------------
__device__ __forceinline__ void pack_row(const f32x4 r0, const f32x4 r1,
                                         const f32x4 r2, const f32x4 r3,
                                         const f32x4 r4, const f32x4 r5,
                                         int g, half8 xf[3]) {
    const half8 hz = {0, 0, 0, 0, 0, 0, 0, 0};
    xf[0] = pack8(r0[0], r0[1], r0[2], r0[3], r1[0], r1[1], r1[2], r1[3]);
    xf[1] = pack8(r2[0], r2[1], r2[2], r2[3], r3[0], r3[1], r3[2], r3[3]);
    if (g < 2) {
        xf[2] = pack8(r4[0], r4[1], r4[2], r4[3], r5[0], r5[1], r5[2], r5[3]);
    } else if (g == 2) {
        // r4 = elems 79,80,81,82 ; k=80..82 + bias-1 at k=83
        xf[2] = pack8(r4[1], r4[2], r4[3], 1.f, 0.f, 0.f, 0.f, 0.f);
    } else {
        xf[2] = hz;
    }
}

// ---------------------------------------------------------------------------
// Main kernel: 2048 blocks x 512 thr, one item per wave. Async-split obs
// loads; self row encoded as a third MFMA row-tile with in-register weight
// reuse; MFMA epilogue (Wvo fp16 A-frags); b128 Wa reads.
// ---------------------------------------------------------------------------
__global__ void __launch_bounds__(512, 3)
main_kernel(const float* __restrict__ sobs,
            const float* __restrict__ nbr,
            const float* __restrict__ edgew,
            const float* __restrict__ b2,
            const float* __restrict__ ba,
            const char* __restrict__ ws,
            float* __restrict__ out) {
    __shared__ __align__(16) char wlds[WS_STAGE];
    int tid = threadIdx.x, w = tid >> 6, lane = tid & 63;
    int b = blockIdx.x * 8 + w;
    int g = lane >> 4, m = lane & 15;
    const f32x4 zz = {0.f, 0.f, 0.f, 0.f};

    // ---- A: issue all per-item global loads FIRST ----
    f32x4 raw[2][6];
    load_raw(nbr + (size_t)b * 2656, g, m, raw);
    f32x4 raw1[6];
    load_raw1(sobs + (size_t)b * 83, g, raw1);
    float ew0 = edgew[b * 32 + m];
    float ew1 = edgew[b * 32 + 16 + m];
    float bav = ba[0];

    // ---- B: stage weights; barrier drains stage AND obs loads together ----
    {
        const f32x4* s4 = (const f32x4*)ws;
        f32x4* d4 = (f32x4*)wlds;
#pragma unroll
        for (int t = 0; t < 6; ++t) d4[t * 512 + tid] = s4[t * 512 + tid];
        if (tid < 132) d4[3072 + tid] = s4[3072 + tid];
        __syncthreads();
    }

    // ---- C: pack frags. Self tile: row 0 = self obs (m==0 cols), else 0 ----
    half8 xf[2][3], xfs[3];
    pack_row(raw[0][0], raw[0][1], raw[0][2], raw[0][3], raw[0][4], raw[0][5], g, xf[0]);
    pack_row(raw[1][0], raw[1][1], raw[1][2], raw[1][3], raw[1][4], raw[1][5], g, xf[1]);
    {
        const half8 hz = {0, 0, 0, 0, 0, 0, 0, 0};
        half8 tmp[3];
        pack_row(raw1[0], raw1[1], raw1[2], raw1[3], raw1[4], raw1[5], g, tmp);
        bool valid = (m == 0);
#pragma unroll
        for (int kt = 0; kt < 3; ++kt) xfs[kt] = valid ? tmp[kt] : hz;
    }

    const half8* W1f = (const half8*)(wlds + WS_W1F);
    const half8* W2f = (const half8*)(wlds + WS_W2F);

    // ---- D: layer 1 (neighbors rn=0,1 + self tile share weight regs) ----
    half8 hf[4][2], hfs[4];
#pragma unroll
    for (int t = 0; t < 4; ++t) {
        int h0 = 2 * t, h1 = 2 * t + 1;
        half8 u0 = W1f[(h0 * 3 + 0) * 64 + lane];
        half8 u1 = W1f[(h0 * 3 + 1) * 64 + lane];
        half8 u2 = W1f[(h0 * 3 + 2) * 64 + lane];
        half8 v0 = W1f[(h1 * 3 + 0) * 64 + lane];
        half8 v1 = W1f[(h1 * 3 + 1) * 64 + lane];
        half8 v2 = W1f[(h1 * 3 + 2) * 64 + lane];
#pragma unroll
        for (int rn = 0; rn < 2; ++rn) {
            f32x4 a = zz, c = zz;
            a = MFMA16(u0, xf[rn][0], a);
            a = MFMA16(u1, xf[rn][1], a);
            a = MFMA16(u2, xf[rn][2], a);
            c = MFMA16(v0, xf[rn][0], c);
            c = MFMA16(v1, xf[rn][1], c);
            c = MFMA16(v2, xf[rn][2], c);
            hf[t][rn] = pack8(
                fmaxf(a[0], 0.f), fmaxf(a[1], 0.f), fmaxf(a[2], 0.f), fmaxf(a[3], 0.f),
                fmaxf(c[0], 0.f), fmaxf(c[1], 0.f), fmaxf(c[2], 0.f), fmaxf(c[3], 0.f));
        }
        {   // self tile, same weights (already in registers)
            f32x4 a = zz, c = zz;
            a = MFMA16(u0, xfs[0], a);
            a = MFMA16(u1, xfs[1], a);
            a = MFMA16(u2, xfs[2], a);
            c = MFMA16(v0, xfs[0], c);
            c = MFMA16(v1, xfs[1], c);
            c = MFMA16(v2, xfs[2], c);
            hfs[t] = pack8(
                fmaxf(a[0], 0.f), fmaxf(a[1], 0.f), fmaxf(a[2], 0.f), fmaxf(a[3], 0.f),
                fmaxf(c[0], 0.f), fmaxf(c[1], 0.f), fmaxf(c[2], 0.f), fmaxf(c[3], 0.f));
        }
    }

    // ---- E: layer 2 + tanh; self path folds straight into es ----
    const f32x4* Wasf2 = (const f32x4*)(wlds + WS_WASF);
    float I[4][2][4];
    float es_acc = 0.f;
#pragma unroll
    for (int om = 0; om < 4; ++om) {
        half8 w0 = W2f[(om * 4 + 0) * 64 + lane];
        half8 w1 = W2f[(om * 4 + 1) * 64 + lane];
        half8 w2 = W2f[(om * 4 + 2) * 64 + lane];
        half8 w3 = W2f[(om * 4 + 3) * 64 + lane];
        float b2v[4];
#pragma unroll
        for (int r = 0; r < 4; ++r) b2v[r] = b2[16 * om + 4 * g + r];
#pragma unroll
        for (int rn = 0; rn < 2; ++rn) {
            f32x4 a = zz;
            a = MFMA16(w0, hf[0][rn], a);
            a = MFMA16(w1, hf[1][rn], a);
            a = MFMA16(w2, hf[2][rn], a);
            a = MFMA16(w3, hf[3][rn], a);
#pragma unroll
            for (int r = 0; r < 4; ++r) {
                float y = a[r] + b2v[r];
                float e = __expf(2.f * y);
                I[om][rn][r] = fmaf(-2.f, __builtin_amdgcn_rcpf(e + 1.f), 1.f);
            }
        }
        {   // self: tanh + dot with Wa_self (valid in m==0 lanes)
            f32x4 a = zz;
            a = MFMA16(w0, hfs[0], a);
            a = MFMA16(w1, hfs[1], a);
            a = MFMA16(w2, hfs[2], a);
            a = MFMA16(w3, hfs[3], a);
            f32x4 was = Wasf2[om * 64 + lane];
#pragma unroll
            for (int r = 0; r < 4; ++r) {
                float y = a[r] + b2v[r];
                float e = __expf(2.f * y);
                float iv = fmaf(-2.f, __builtin_amdgcn_rcpf(e + 1.f), 1.f);
                es_acc = fmaf(iv, was[r], es_acc);
            }
        }
    }
    // g-reduce then broadcast from lane 0 (g0,m0 holds the full self dot)
    es_acc += __shfl_xor(es_acc, 16);
    es_acc += __shfl_xor(es_acc, 32);
    float esb = __shfl(es_acc, 0);

    const f32x4* Wafn2 = (const f32x4*)(wlds + WS_WAFN);
    const half8* Wvo16 = (const half8*)(wlds + WS_WVO16);
    const float* bvo   = (const float*)(wlds + WS_BVO);

    // attention logits: en[row] = dot(I[row], Wa_nbr) — 4 b128 LDS reads
    float en0 = 0.f, en1 = 0.f;
#pragma unroll
    for (int om = 0; om < 4; ++om) {
        f32x4 wa = Wafn2[om * 64 + lane];
#pragma unroll
        for (int r = 0; r < 4; ++r) {
            en0 = fmaf(I[om][0][r], wa[r], en0);
            en1 = fmaf(I[om][1][r], wa[r], en1);
        }
    }
    en0 += __shfl_xor(en0, 16); en0 += __shfl_xor(en0, 32);
    en1 += __shfl_xor(en1, 16); en1 += __shfl_xor(en1, 32);

    float e0 = esb + en0 + bav; e0 = (e0 > 0.f) ? e0 : 0.2f * e0; e0 *= ew0;
    float e1 = esb + en1 + bav; e1 = (e1 > 0.f) ? e1 : 0.2f * e1; e1 *= ew1;

    // softmax over 32 neighbors; |e| bounded (~7) -> fp32-safe w/o max-sub
    float p0 = __expf(e0), p1 = __expf(e1);
    float s = p0 + p1;
#pragma unroll
    for (int msk = 1; msk <= 8; msk <<= 1) s += __shfl_xor(s, msk);
    float inv = __builtin_amdgcn_rcpf(s);
    float a0 = p0 * inv, a1 = p1 * inv;

    // values: V' = Wvo^T @ I^T (4 MFMAs). B-frag straight from I registers.
    half8 vf[2][2];
#pragma unroll
    for (int kt = 0; kt < 2; ++kt)
#pragma unroll
        for (int rn = 0; rn < 2; ++rn)
            vf[kt][rn] = pack8(I[2 * kt][rn][0], I[2 * kt][rn][1],
                               I[2 * kt][rn][2], I[2 * kt][rn][3],
                               I[2 * kt + 1][rn][0], I[2 * kt + 1][rn][1],
                               I[2 * kt + 1][rn][2], I[2 * kt + 1][rn][3]);

    half8 wv0 = Wvo16[lane];
    half8 wv1 = Wvo16[64 + lane];
    f32x4 acc0 = zz, acc1 = zz;
    acc0 = MFMA16(wv0, vf[0][0], acc0);
    acc0 = MFMA16(wv1, vf[1][0], acc0);
    acc1 = MFMA16(wv0, vf[0][1], acc1);
    acc1 = MFMA16(wv1, vf[1][1], acc1);
    // lane (g,m) reg r: acc0[r] = V'[j=4g+r][neighbor m], acc1: neighbor 16+m

    // alpha-weight per lane, reduce over the 16 m-lanes (4 shuffle steps)
    f32x4 v4;
#pragma unroll
    for (int r = 0; r < 4; ++r) v4[r] = a0 * acc0[r] + a1 * acc1[r];
#pragma unroll
    for (int msk = 1; msk <= 8; msk <<= 1) {
#pragma unroll
        for (int r = 0; r < 4; ++r) v4[r] += __shfl_xor(v4[r], msk);
    }

    if (m == 0) {
        f32x4 bb = *(const f32x4*)(bvo + 4 * g);
        *(f32x4*)(out + (size_t)b * 16 + 4 * g) = v4 + bb;
    }
}

// ---------------------------------------------------------------------------
extern "C" void kernel_launch(void* const* d_in, const int* in_sizes, int n_in,
                              void* d_out, int out_size, void* d_ws, size_t ws_size,
                              hipStream_t stream) {
    const float* self_obs = (const float*)d_in[0];
    const float* nbr      = (const float*)d_in[1];
    const float* ew       = (const float*)d_in[2];
    const float* W1       = (const float*)d_in[3];
    const float* b1       = (const float*)d_in[4];
    const float* W2       = (const float*)d_in[5];
    const float* b2       = (const float*)d_in[6];
    const float* Wa       = (const float*)d_in[7];
    const float* ba       = (const float*)d_in[8];
    const float* Wv       = (const float*)d_in[9];
    const float* bv       = (const float*)d_in[10];
    const float* Wo       = (const float*)d_in[11];
    const float* bo       = (const float*)d_in[12];
    char* ws = (char*)d_ws;
    float* out = (float*)d_out;

    prep_kernel<<<93, 256, 0, stream>>>(W1, b1, W2, Wv, Wa, Wo, bv, bo, ws);
    main_kernel<<<2048, 512, 0, stream>>>(self_obs, nbr, ew, b2, ba, ws, out);
}